// Round 1
// baseline (4528.169 us; speedup 1.0000x reference)
//
#include <hip/hip_runtime.h>
#include <math.h>

// Problem constants (fixed by setup_inputs)
#define N_   128
#define K_   8
#define C_   16
#define D_   16
#define H_   16
#define W_   16
#define SPT  (D_*H_*W_)   // 4096 voxels per channel
#define SLICE (H_*W_)     // 256 voxels per z-slice
#define CO3  (3*C_)       // 48 iou output channels
#define OUT_HALF (N_*C_*SPT)  // 8388608 elements for h (c follows)

__device__ __forceinline__ float sigmoidf_(float x) {
    return 1.f / (1.f + __expf(-x));
}
__device__ __forceinline__ float tanhf_(float x) {
    // tanh via exp(2x); clamp to avoid inf/inf NaN (saturated long before 15)
    x = fminf(fmaxf(x, -15.f), 15.f);
    float t = __expf(2.f * x);
    return (t - 1.f) / (t + 1.f);
}

// ---------------------------------------------------------------------------
// Kernel 0: transpose weights so the hot inner loop reads co-contiguous
// weight vectors with a wave-uniform address (-> s_load_dwordx16).
//   U_f_w  [co=16][ci=16][k=27] -> wfT  [ci][k][co=16]
//   U_iou_w[co=48][ci=16][k=27] -> wiouT[ci][k][co=48]
// ---------------------------------------------------------------------------
__global__ void transpose_w(const float* __restrict__ wf,
                            const float* __restrict__ wiou,
                            float* __restrict__ wfT,
                            float* __restrict__ wiouT)
{
    int t = blockIdx.x * blockDim.x + threadIdx.x;
    if (t < C_ * C_ * 27) {
        int co = t / (C_ * 27);
        int r  = t % (C_ * 27);
        int ci = r / 27, k = r % 27;
        wfT[(ci * 27 + k) * C_ + co] = wf[t];
    }
    if (t < CO3 * C_ * 27) {
        int co = t / (C_ * 27);
        int r  = t % (C_ * 27);
        int ci = r / 27, k = r % 27;
        wiouT[(ci * 27 + k) * CO3 + co] = wiou[t];
    }
}

// ---------------------------------------------------------------------------
// Kernel 1: per (n, z) block. Loop k=0..7:
//   stage mailbox_h[n,k,:, z-1..z+1, :, :] in LDS (zero z-halo),
//   conv3d (16->16) -> sigmoid -> * mailbox_c, accumulate c_sum;
//   accumulate h_child = sum_k mailbox_h (center slice from LDS).
// Thread t owns position (y = t>>4, x = t&15) and all 16 output channels.
// ---------------------------------------------------------------------------
__global__ __launch_bounds__(256) void fuse_reduce(
    const float* __restrict__ mh, const float* __restrict__ mc,
    const float* __restrict__ wfT,
    float* __restrict__ h_child, float* __restrict__ c_sum)
{
    __shared__ float lds[C_ * 3 * SLICE];   // 48 KB -> 3 blocks/CU
    const int n = blockIdx.x / D_;
    const int z = blockIdx.x % D_;
    const int t = threadIdx.x;
    const int y = t >> 4, x = t & 15;

    float csum[C_], hsum[C_];
#pragma unroll
    for (int c = 0; c < C_; ++c) { csum[c] = 0.f; hsum[c] = 0.f; }

    for (int k = 0; k < K_; ++k) {
        const float* src = mh + ((size_t)(n * K_ + k)) * (C_ * SPT);
        __syncthreads();   // protect LDS from previous iteration's readers
        for (int idx = t; idx < C_ * 3 * SLICE; idx += 256) {
            int ci  = idx / (3 * SLICE);
            int rem = idx % (3 * SLICE);
            int zz  = rem / SLICE;          // 0..2 -> z-1..z+1
            int p   = rem % SLICE;
            int zsrc = z + zz - 1;
            float v = 0.f;
            if (zsrc >= 0 && zsrc < D_) v = src[ci * SPT + zsrc * SLICE + p];
            lds[idx] = v;
        }
        __syncthreads();

        // h_child accumulation (center slice), fully unrolled -> registers
#pragma unroll
        for (int ci = 0; ci < C_; ++ci)
            hsum[ci] += lds[ci * (3 * SLICE) + SLICE + t];

        float acc[C_];
#pragma unroll
        for (int c = 0; c < C_; ++c) acc[c] = 0.f;

        // conv: ci rolled (keeps code size sane), 27 taps x 16 co unrolled
#pragma unroll 1
        for (int ci = 0; ci < C_; ++ci) {
            const float* w = wfT + ci * 27 * C_;
            const float* l = lds + ci * (3 * SLICE);
#pragma unroll
            for (int kz = 0; kz < 3; ++kz) {
#pragma unroll
                for (int ky = 0; ky < 3; ++ky) {
                    int  yy  = y + ky - 1;
                    bool oky = (unsigned)yy < (unsigned)H_;
#pragma unroll
                    for (int kx = 0; kx < 3; ++kx) {
                        int  xx = x + kx - 1;
                        bool ok = oky && ((unsigned)xx < (unsigned)W_);
                        float v = ok ? l[kz * SLICE + ((yy & 15) << 4) + (xx & 15)]
                                     : 0.f;
                        const float* wk = w + ((kz * 3 + ky) * 3 + kx) * C_;
#pragma unroll
                        for (int co = 0; co < C_; ++co)
                            acc[co] = fmaf(v, wk[co], acc[co]);
                    }
                }
            }
        }

        const float* csrc = mc + ((size_t)(n * K_ + k)) * (C_ * SPT)
                               + z * SLICE + t;
#pragma unroll
        for (int co = 0; co < C_; ++co) {
            float f = sigmoidf_(acc[co]);
            csum[co] = fmaf(f, csrc[co * SPT], csum[co]);
        }
    }

    size_t base = ((size_t)n * C_) * SPT + z * SLICE + t;
#pragma unroll
    for (int c = 0; c < C_; ++c) {
        h_child[base + c * SPT] = hsum[c];
        c_sum[base + c * SPT]   = csum[c];
    }
}

// ---------------------------------------------------------------------------
// Kernel 2: per (n, z) block. Stage h_child 3 z-slices, conv3d (16->48),
// add bias, apply gates, write h and c.
// ---------------------------------------------------------------------------
__global__ __launch_bounds__(256) void iou_gate(
    const float* __restrict__ h_child, const float* __restrict__ c_sum,
    const float* __restrict__ wiouT, const float* __restrict__ biou,
    float* __restrict__ out)
{
    __shared__ float lds[C_ * 3 * SLICE];
    const int n = blockIdx.x / D_;
    const int z = blockIdx.x % D_;
    const int t = threadIdx.x;
    const int y = t >> 4, x = t & 15;

    const float* src = h_child + (size_t)n * (C_ * SPT);
    for (int idx = t; idx < C_ * 3 * SLICE; idx += 256) {
        int ci  = idx / (3 * SLICE);
        int rem = idx % (3 * SLICE);
        int zz  = rem / SLICE;
        int p   = rem % SLICE;
        int zsrc = z + zz - 1;
        float v = 0.f;
        if (zsrc >= 0 && zsrc < D_) v = src[ci * SPT + zsrc * SLICE + p];
        lds[idx] = v;
    }
    __syncthreads();

    float acc[CO3];
#pragma unroll
    for (int c = 0; c < CO3; ++c) acc[c] = 0.f;

#pragma unroll 1
    for (int ci = 0; ci < C_; ++ci) {
        const float* w = wiouT + ci * 27 * CO3;
        const float* l = lds + ci * (3 * SLICE);
#pragma unroll
        for (int kz = 0; kz < 3; ++kz) {
#pragma unroll
            for (int ky = 0; ky < 3; ++ky) {
                int  yy  = y + ky - 1;
                bool oky = (unsigned)yy < (unsigned)H_;
#pragma unroll
                for (int kx = 0; kx < 3; ++kx) {
                    int  xx = x + kx - 1;
                    bool ok = oky && ((unsigned)xx < (unsigned)W_);
                    float v = ok ? l[kz * SLICE + ((yy & 15) << 4) + (xx & 15)]
                                 : 0.f;
                    const float* wk = w + ((kz * 3 + ky) * 3 + kx) * CO3;
#pragma unroll
                    for (int co = 0; co < CO3; ++co)
                        acc[co] = fmaf(v, wk[co], acc[co]);
                }
            }
        }
    }

    const size_t pbase = (size_t)z * SLICE + t;
    const size_t obase = ((size_t)n * C_) * SPT + pbase;
#pragma unroll
    for (int c = 0; c < C_; ++c) {
        float iv = acc[c]      + biou[(c)      * SPT + pbase];
        float ov = acc[c + 16] + biou[(c + 16) * SPT + pbase];
        float uv = acc[c + 32] + biou[(c + 32) * SPT + pbase];
        float cs = c_sum[obase + c * SPT];
        float cc = sigmoidf_(iv) * tanhf_(uv) + cs;
        float hh = sigmoidf_(ov) * tanhf_(cc);
        out[obase + c * SPT]            = hh;
        out[OUT_HALF + obase + c * SPT] = cc;
    }
}

// ---------------------------------------------------------------------------
extern "C" void kernel_launch(void* const* d_in, const int* in_sizes, int n_in,
                              void* d_out, int out_size, void* d_ws, size_t ws_size,
                              hipStream_t stream)
{
    const float* mh   = (const float*)d_in[0];   // mailbox_h [128,8,16,16,16,16]
    const float* mc   = (const float*)d_in[1];   // mailbox_c
    const float* wf   = (const float*)d_in[2];   // U_f_w   [16,16,3,3,3]
    const float* wiou = (const float*)d_in[3];   // U_iou_w [48,16,3,3,3]
    const float* biou = (const float*)d_in[4];   // b_iou   [48,16,16,16]
    float* out = (float*)d_out;

    // workspace layout (bytes):
    //   0        : wfT    (6912 f)   = 27648 B
    //   27648    : wiouT  (20736 f)  = 82944 B
    //   131072   : h_child (8388608 f) = 32 MiB
    //   33685504 : c_sum   (8388608 f) = 32 MiB
    char* ws = (char*)d_ws;
    float* wfT     = (float*)(ws);
    float* wiouT   = (float*)(ws + 27648);
    float* h_child = (float*)(ws + 131072);
    float* c_sum   = (float*)(ws + 131072 + (size_t)OUT_HALF * 4);

    hipLaunchKernelGGL(transpose_w, dim3(81), dim3(256), 0, stream,
                       wf, wiou, wfT, wiouT);
    hipLaunchKernelGGL(fuse_reduce, dim3(N_ * D_), dim3(256), 0, stream,
                       mh, mc, wfT, h_child, c_sum);
    hipLaunchKernelGGL(iou_gate, dim3(N_ * D_), dim3(256), 0, stream,
                       h_child, c_sum, wiouT, biou, out);
}

// Round 2
// 922.687 us; speedup vs baseline: 4.9076x; 4.9076x over previous
//
#include <hip/hip_runtime.h>

#define N_   128
#define K_   8
#define C_   16
#define D_   16
#define H_   16
#define W_   16
#define SPT  4096
#define OUT_HALF (N_*C_*SPT)   // 8388608

typedef unsigned short u16;
typedef __attribute__((ext_vector_type(4))) short bf16x4;
typedef __attribute__((ext_vector_type(8))) short bf16x8;
typedef __attribute__((ext_vector_type(4))) float f32x4;

__device__ __forceinline__ u16 f2bf(float f) {
    unsigned u = __builtin_bit_cast(unsigned, f);
    u += 0x7fffu + ((u >> 16) & 1u);      // RNE
    return (u16)(u >> 16);
}
__device__ __forceinline__ float bf2f(u16 s) {
    unsigned u = ((unsigned)s) << 16;
    return __builtin_bit_cast(float, u);
}
__device__ __forceinline__ float fsig(float x) {
    return __builtin_amdgcn_rcpf(1.f + __expf(-x));
}
__device__ __forceinline__ float ftanh(float x) {
    // tanh(x) = 1 - 2/(1+e^{2x}); saturates correctly at +-inf exp
    float r = __builtin_amdgcn_rcpf(1.f + __expf(2.f * x));
    return fmaf(-2.f, r, 1.f);
}

// ---------------------------------------------------------------------------
// Pack conv weights into MFMA A-fragments (bf16).
// k-slot convention (same for A and B, any bijection is valid since A/B
// fragment layouts are symmetric): lane l (co = l&15, h = l>>4),
// slot j<4  -> tap 2*tp,   ci = 4h + j
// slot j>=4 -> tap 2*tp+1, ci = 4h + (j-4)   (tap 27 = zero pad)
// wfA  [14][64][8] bf16 ; wiouA [3][14][64][8]
// ---------------------------------------------------------------------------
__global__ void prep_pack(const float* __restrict__ wf,
                          const float* __restrict__ wiou,
                          u16* __restrict__ wfA, u16* __restrict__ wiouA)
{
    int p = blockIdx.x * 256 + threadIdx.x;
    if (p < 7168) {
        int tp = p >> 9, l = (p >> 3) & 63, j = p & 7;
        int co = l & 15, hh = l >> 4;
        int tau = 2 * tp + (j >> 2);
        int ci  = 4 * hh + (j & 3);
        float v = (tau < 27) ? wf[(co * 16 + ci) * 27 + tau] : 0.f;
        wfA[p] = f2bf(v);
    }
    if (p < 21504) {
        int ct = p / 7168, p2 = p % 7168;
        int tp = p2 >> 9, l = (p2 >> 3) & 63, j = p2 & 7;
        int co = ct * 16 + (l & 15), hh = l >> 4;
        int tau = 2 * tp + (j >> 2);
        int ci  = 4 * hh + (j & 3);
        float v = (tau < 27) ? wiou[(co * 16 + ci) * 27 + tau] : 0.f;
        wiouA[p] = f2bf(v);
    }
}

// LDS geometry (shorts): zero row [0,320) ; slice s at 320 + s*5120,
// voxel stride 20 shorts (40 B -> bank-spread 10v%32, 8B-aligned b64 reads),
// row stride 320 shorts, slice = 16 rows. Total 31040 shorts = 62080 B.
#define LSLICE 5120
#define LROW   320
#define LVOX   20

// Load one bf16x4 tap-half: tap tau (unrolled-constant), row y (unrolled-
// constant). base pointers already include per-lane vx0 = x*20 + h*4.
#define LOADHALF(tau, yy, dst) do {                                          \
    const int dz_ = (tau) / 9 - 1, dy_ = ((tau) % 9) / 3 - 1,                \
              dx_ = (tau) % 3 - 1;                                           \
    const int yt_ = (yy) + dy_;                                              \
    const u16* p_;                                                           \
    if (yt_ < 0 || yt_ > 15) p_ = zb + dx_ * LVOX;                           \
    else p_ = (dz_ == -1 ? sb0 : (dz_ == 0 ? sb1 : sb2))                     \
              + yt_ * LROW + dx_ * LVOX;                                     \
    dst = *(const bf16x4*)p_;                                                \
    if (dx_ == -1) { if (x == 0)  dst = z4; }                                \
    if (dx_ ==  1) { if (x == 15) dst = z4; }                                \
} while (0)

// ---------------------------------------------------------------------------
// K1: per (n, z-group-of-4) block, 4 waves (one z-slice each).
// Loop k: stage mailbox_h fp32 -> bf16 LDS (voxel-major, padded stride),
// f-conv via 14 MFMA per row, f=sigmoid, csum += f*mc, hsum += mh.
// Writes h_child (bf16, channel-last) and c_sum (fp32, channel-last).
// ---------------------------------------------------------------------------
__global__ __launch_bounds__(256, 2) void fuse_reduce_mfma(
    const float* __restrict__ mh, const float* __restrict__ mc,
    const u16* __restrict__ wfA,
    u16* __restrict__ h_child, float* __restrict__ c_sum)
{
    __shared__ u16 S[31040];
    const int bid = blockIdx.x;
    const int n = bid >> 2, zg = bid & 3;
    const int t = threadIdx.x;
    const int w = t >> 6, l = t & 63;
    const int x = l & 15, h = l >> 4;
    const int z = zg * 4 + w;
    const bf16x4 z4 = {0, 0, 0, 0};

    if (t < 160) ((unsigned*)S)[t] = 0u;   // zero pad row (640 B)

    bf16x8 af[14];
#pragma unroll
    for (int tp = 0; tp < 14; ++tp)
        af[tp] = ((const bf16x8*)wfA)[tp * 64 + l];

    const int vx0 = x * LVOX + h * 4;
    const u16* sb0 = S + 320 + (w    ) * LSLICE + vx0;
    const u16* sb1 = S + 320 + (w + 1) * LSLICE + vx0;
    const u16* sb2 = S + 320 + (w + 2) * LSLICE + vx0;
    const u16* zb  = S + vx0;

    float csum[16][4], hsum[16][4];
#pragma unroll
    for (int y = 0; y < 16; ++y)
#pragma unroll
        for (int r = 0; r < 4; ++r) { csum[y][r] = 0.f; hsum[y][r] = 0.f; }

    const float* mcp = mc + (size_t)n * 524288 + h * 16384 + z * 256 + x;

#pragma unroll 1
    for (int k = 0; k < K_; ++k) {
        __syncthreads();                      // previous compute done
        const float* src = mh + (size_t)(n * 8 + k) * 65536;
        // stage: e over [zz(6)][cp(8)][y(16)][x4(4)] -> coalesced float4 loads
#pragma unroll
        for (int u = 0; u < 12; ++u) {
            int e  = u * 256 + t;
            int x4 = e & 3, y = (e >> 2) & 15, cp = (e >> 6) & 7, zz = e >> 9;
            int zsrc = zg * 4 + zz - 1;
            unsigned* dp = (unsigned*)(S + 320 + zz * LSLICE + y * LROW
                                       + x4 * (4 * LVOX) + cp * 2);
            if ((unsigned)zsrc < 16u) {
                const float4 a = *(const float4*)(src + (2 * cp) * 4096
                                                  + zsrc * 256 + y * 16 + x4 * 4);
                const float4 b = *(const float4*)(src + (2 * cp + 1) * 4096
                                                  + zsrc * 256 + y * 16 + x4 * 4);
                dp[0]  = (unsigned)f2bf(a.x) | ((unsigned)f2bf(b.x) << 16);
                dp[10] = (unsigned)f2bf(a.y) | ((unsigned)f2bf(b.y) << 16);
                dp[20] = (unsigned)f2bf(a.z) | ((unsigned)f2bf(b.z) << 16);
                dp[30] = (unsigned)f2bf(a.w) | ((unsigned)f2bf(b.w) << 16);
            } else {
                dp[0] = 0u; dp[10] = 0u; dp[20] = 0u; dp[30] = 0u;
            }
        }
        __syncthreads();

        const float* mck = mcp + k * 65536;
#pragma unroll
        for (int y = 0; y < 16; ++y) {
            f32x4 acc = {0.f, 0.f, 0.f, 0.f};
#pragma unroll
            for (int tp = 0; tp < 14; ++tp) {
                bf16x4 va, vb;
                LOADHALF(2 * tp, y, va);
                if (2 * tp + 1 < 27) { LOADHALF(2 * tp + 1, y, vb); }
                else vb = va;   // A-half is zero for the pad tap
                bf16x8 bfr = __builtin_shufflevector(va, vb, 0,1,2,3,4,5,6,7);
                acc = __builtin_amdgcn_mfma_f32_16x16x32_bf16(af[tp], bfr, acc,
                                                              0, 0, 0);
            }
            // h_child accumulation from center slice (own voxel)
            bf16x4 hv = *(const bf16x4*)(sb1 + y * LROW);
#pragma unroll
            for (int r = 0; r < 4; ++r) hsum[y][r] += bf2f((u16)hv[r]);
            // f = sigmoid(conv), csum += f * mailbox_c
#pragma unroll
            for (int r = 0; r < 4; ++r)
                csum[y][r] = fmaf(fsig(acc[r]), mck[y * 16 + r * 4096],
                                  csum[y][r]);
        }
    }

    // write h_child (bf16 channel-last) and c_sum (fp32 channel-last)
    const size_t vb0 = ((size_t)(n * 16 + z)) * 256 + x;
#pragma unroll
    for (int y = 0; y < 16; ++y) {
        size_t idx = (vb0 + y * 16) * 16 + 4 * h;
        uint2 hp;
        hp.x = (unsigned)f2bf(hsum[y][0]) | ((unsigned)f2bf(hsum[y][1]) << 16);
        hp.y = (unsigned)f2bf(hsum[y][2]) | ((unsigned)f2bf(hsum[y][3]) << 16);
        *(uint2*)(h_child + idx) = hp;
        f32x4 cv = {csum[y][0], csum[y][1], csum[y][2], csum[y][3]};
        *(f32x4*)(c_sum + idx) = cv;
    }
}

// ---------------------------------------------------------------------------
// K2: per (n, z-group-of-4) block. Stage h_child slab (straight bf16 copy),
// iou conv = 3 co-tiles x 14 MFMA per row (B shared), bias + gates, store.
// ---------------------------------------------------------------------------
__global__ __launch_bounds__(256, 2) void iou_gate_mfma(
    const u16* __restrict__ hc, const float* __restrict__ c_sum,
    const u16* __restrict__ wiouA, const float* __restrict__ biou,
    float* __restrict__ out)
{
    __shared__ u16 S[31040];
    const int bid = blockIdx.x;
    const int n = bid >> 2, zg = bid & 3;
    const int t = threadIdx.x;
    const int w = t >> 6, l = t & 63;
    const int x = l & 15, h = l >> 4;
    const int z = zg * 4 + w;
    const bf16x4 z4 = {0, 0, 0, 0};

    if (t < 160) ((unsigned*)S)[t] = 0u;

    bf16x8 aw0[14], aw1[14], aw2[14];
#pragma unroll
    for (int tp = 0; tp < 14; ++tp) {
        aw0[tp] = ((const bf16x8*)wiouA)[(0 * 14 + tp) * 64 + l];
        aw1[tp] = ((const bf16x8*)wiouA)[(1 * 14 + tp) * 64 + l];
        aw2[tp] = ((const bf16x8*)wiouA)[(2 * 14 + tp) * 64 + l];
    }

    // stage 6 slices (straight copy, 32 B per voxel)
#pragma unroll
    for (int q = 0; q < 6; ++q) {
        int fv = q * 256 + t;
        int zz = fv >> 8, yy = (fv >> 4) & 15, xx = fv & 15;
        int zsrc = zg * 4 + zz - 1;
        uint4 d0 = {0,0,0,0}, d1 = {0,0,0,0};
        if ((unsigned)zsrc < 16u) {
            const uint4* g = (const uint4*)(hc
                + (((size_t)(n * 16 + zsrc)) * 256 + yy * 16 + xx) * 16);
            d0 = g[0]; d1 = g[1];
        }
        uint2* dp = (uint2*)(S + 320 + zz * LSLICE + yy * LROW + xx * LVOX);
        dp[0] = make_uint2(d0.x, d0.y);
        dp[1] = make_uint2(d0.z, d0.w);
        dp[2] = make_uint2(d1.x, d1.y);
        dp[3] = make_uint2(d1.z, d1.w);
    }
    __syncthreads();

    const int vx0 = x * LVOX + h * 4;
    const u16* sb0 = S + 320 + (w    ) * LSLICE + vx0;
    const u16* sb1 = S + 320 + (w + 1) * LSLICE + vx0;
    const u16* sb2 = S + 320 + (w + 2) * LSLICE + vx0;
    const u16* zb  = S + vx0;

    const unsigned bvox0 = z * 256 + x;
    const float* bp0 = biou + h * 16384 + bvox0;
    const float* cs0 = c_sum + (((size_t)(n * 16 + z)) * 256 + x) * 16 + 4 * h;
    float* oh0 = out + ((size_t)(n * 16 + 4 * h)) * 4096 + bvox0;

#pragma unroll
    for (int y = 0; y < 16; ++y) {
        f32x4 ai = {0.f,0.f,0.f,0.f}, ao = {0.f,0.f,0.f,0.f},
              au = {0.f,0.f,0.f,0.f};
#pragma unroll
        for (int tp = 0; tp < 14; ++tp) {
            bf16x4 va, vb;
            LOADHALF(2 * tp, y, va);
            if (2 * tp + 1 < 27) { LOADHALF(2 * tp + 1, y, vb); }
            else vb = va;
            bf16x8 bfr = __builtin_shufflevector(va, vb, 0,1,2,3,4,5,6,7);
            ai = __builtin_amdgcn_mfma_f32_16x16x32_bf16(aw0[tp], bfr, ai, 0,0,0);
            ao = __builtin_amdgcn_mfma_f32_16x16x32_bf16(aw1[tp], bfr, ao, 0,0,0);
            au = __builtin_amdgcn_mfma_f32_16x16x32_bf16(aw2[tp], bfr, au, 0,0,0);
        }
        const float* bp = bp0 + y * 16;
        f32x4 cs = *(const f32x4*)(cs0 + y * 256);   // (y*16 voxels)*16ch
        float* oh = oh0 + y * 16;
#pragma unroll
        for (int r = 0; r < 4; ++r) {
            float iv = ai[r] + bp[r * 4096];
            float ov = ao[r] + bp[65536 + r * 4096];
            float uv = au[r] + bp[131072 + r * 4096];
            float cc = fsig(iv) * ftanh(uv) + cs[r];
            float hh = fsig(ov) * ftanh(cc);
            oh[(size_t)r * 4096] = hh;
            oh[OUT_HALF + (size_t)r * 4096] = cc;
        }
    }
}

// ---------------------------------------------------------------------------
extern "C" void kernel_launch(void* const* d_in, const int* in_sizes, int n_in,
                              void* d_out, int out_size, void* d_ws, size_t ws_size,
                              hipStream_t stream)
{
    const float* mh   = (const float*)d_in[0];
    const float* mc   = (const float*)d_in[1];
    const float* wf   = (const float*)d_in[2];
    const float* wiou = (const float*)d_in[3];
    const float* biou = (const float*)d_in[4];
    float* out = (float*)d_out;

    // ws layout: wfA @0 (14336B), wiouA @16384 (43008B),
    // h_child bf16 @65536 (16 MiB), c_sum fp32 @16842752 (32 MiB)
    char* ws = (char*)d_ws;
    u16*   wfA     = (u16*)(ws);
    u16*   wiouA   = (u16*)(ws + 16384);
    u16*   h_child = (u16*)(ws + 65536);
    float* c_sum   = (float*)(ws + 65536 + (size_t)OUT_HALF * 2);

    hipLaunchKernelGGL(prep_pack, dim3(84), dim3(256), 0, stream,
                       wf, wiou, wfA, wiouA);
    hipLaunchKernelGGL(fuse_reduce_mfma, dim3(512), dim3(256), 0, stream,
                       mh, mc, wfA, h_child, c_sum);
    hipLaunchKernelGGL(iou_gate_mfma, dim3(512), dim3(256), 0, stream,
                       h_child, c_sum, wiouA, biou, out);
}